// Round 5
// baseline (965.148 us; speedup 1.0000x reference)
//
#include <hip/hip_runtime.h>

// Model: conv(32x2,s2) -> conv(32x9,s2) -> GRU encoder (105 steps) ->
//        attention decoder (63 steps) -> fc.  B=64,H=128,V=32.

typedef float f32x4 __attribute__((ext_vector_type(4)));
typedef short s16x8 __attribute__((ext_vector_type(8)));

static __device__ __forceinline__ unsigned short f2b(float f) {
  unsigned int u = __float_as_uint(f);
  unsigned int r = u + 0x7fffu + ((u >> 16) & 1u);
  return (unsigned short)(r >> 16);
}
static __device__ __forceinline__ float sigmoidf_(float x) {
  return 1.0f / (1.0f + __expf(-x));
}
static __device__ __forceinline__ float tanhf_(float x) {
  float ax = fabsf(x);
  float t = __expf(-2.0f * ax);
  float r = (1.0f - t) / (1.0f + t);
  return x >= 0.0f ? r : -r;
}
static __device__ __forceinline__ float blo(unsigned int w) {
  return __uint_as_float(w << 16);
}
static __device__ __forceinline__ float bhi(unsigned int w) {
  return __uint_as_float(w & 0xffff0000u);
}
// lgkmcnt-only barrier: does NOT drain vmcnt, so global prefetch loads stay
// in flight across phase barriers (only LDS ordering is needed).
static __device__ __forceinline__ void barL() {
  asm volatile("s_waitcnt lgkmcnt(0)" ::: "memory");
  __builtin_amdgcn_s_barrier();
  asm volatile("" ::: "memory");
}

// ---------------- weight pre-transforms (re-run every launch; ws is re-poisoned) ----
__global__ __launch_bounds__(256) void prep_kernel(
    const float* __restrict__ w2, const float* __restrict__ wih,
    const float* __restrict__ whh, const float* __restrict__ dwhh,
    const float* __restrict__ dwih,
    unsigned short* __restrict__ wt2, unsigned short* __restrict__ wihB,
    unsigned int* __restrict__ wpe, unsigned int* __restrict__ wpd,
    float* __restrict__ wdT) {
  int idx = blockIdx.x * 256 + threadIdx.x;
  if (idx < 294912) {
    int ci = idx & 31;
    int n = (idx >> 5) & 31;
    int kk = idx >> 10;          // kt*9+kf
    int kf = kk % 9, kt = kk / 9;
    wt2[idx] = f2b(w2[((n * 32 + ci) * 32 + kt) * 9 + kf]);
  } else if (idx < 737280) {
    int i = idx - 294912;
    wihB[i] = f2b(wih[i]);
  } else if (idx < 761856) {
    int i = idx - 737280;
    int j = i % 384, k2 = i / 384;
    unsigned int lo = f2b(whh[j * 128 + 2 * k2]);
    unsigned int hi = f2b(whh[j * 128 + 2 * k2 + 1]);
    wpe[i] = lo | (hi << 16);
  } else if (idx < 786432) {
    int i = idx - 761856;
    int j = i % 384, k2 = i / 384;
    unsigned int lo = f2b(dwhh[j * 128 + 2 * k2]);
    unsigned int hi = f2b(dwhh[j * 128 + 2 * k2 + 1]);
    wpd[i] = lo | (hi << 16);
  } else if (idx < 798720) {
    int i = idx - 786432;
    int j = i % 384, e = i / 384;
    wdT[i] = dwih[j * 32 + e];
  }
}

// ---------------- conv1 v3: one channel/thread (64 weight VGPRs, 4 waves/SIMD) -----
// v2 kept both channels' weights in registers (128 VGPR -> total 148 -> only
// 2 waves/SIMD resident; VALUBusy 31%).  One channel per thread halves weight
// and accumulator registers; __launch_bounds__(256,4) pins 4 waves/SIMD.
// Identical fmaf order per output -> bitwise-same results and layout.
__global__ __launch_bounds__(256, 4) void conv1_kernel(
    const float* __restrict__ x, const float* __restrict__ mean,
    const float* __restrict__ stdv, const float* __restrict__ w1,
    const float* __restrict__ b1, unsigned short* __restrict__ c1out) {
  __shared__ float ins[46][162];
  __shared__ float meanL[161];
  __shared__ float rstdL[161];
  int tid = threadIdx.x;
  int tt = blockIdx.x;        // 0..30
  int b = blockIdx.y;         // 0..63
  int t0 = tt * 8;
  if (tid < 161) {
    meanL[tid] = mean[tid];
    rstdL[tid] = 1.0f / stdv[tid];
  }
  int c = tid & 31, fs = tid >> 5;   // one channel, 8 f-groups
  float w[64];
  {
    const float4* wp = (const float4*)(w1 + c * 64);
#pragma unroll
    for (int i = 0; i < 16; ++i) {
      float4 v = wp[i];
      w[4 * i] = v.x; w[4 * i + 1] = v.y; w[4 * i + 2] = v.z; w[4 * i + 3] = v.w;
    }
  }
  float bias = b1[c];
  __syncthreads();   // meanL/rstdL ready

  const float* xb = x + ((size_t)b * 512 + 2 * t0) * 161;
  int nrows = 512 - 2 * t0; if (nrows > 46) nrows = 46;
  for (int i = tid; i < 46 * 161; i += 256) {
    int r = i / 161, col = i - r * 161;
    float v = (r < nrows) ? xb[(size_t)r * 161 + col] : 0.0f;
    ins[r][col] = (v - meanL[col]) * rstdL[col];
  }
  __syncthreads();

  int T = 241 - t0; if (T > 8) T = 8;
#pragma unroll
  for (int fi = 0; fi < 10; ++fi) {
    int f = fs + 8 * fi;
    float acc[8];
#pragma unroll
    for (int t = 0; t < 8; ++t) acc[t] = bias;
#pragma unroll
    for (int r = 0; r < 46; ++r) {
      float2 v = *(const float2*)&ins[r][2 * f];
#pragma unroll
      for (int t = 0; t < 8; ++t) {
        const int kt = r - 2 * t;
        if (kt >= 0 && kt < 32) {
          acc[t] = fmaf(v.x, w[2 * kt], acc[t]);
          acc[t] = fmaf(v.y, w[2 * kt + 1], acc[t]);
        }
      }
    }
#pragma unroll
    for (int t = 0; t < 8; ++t) {
      if (t < T) {
        float a = acc[t] > 0.0f ? acc[t] : 0.0f;
        c1out[(((size_t)b * 241 + t0 + t) * 80 + f) * 32 + c] = f2b(a);
      }
    }
  }
}

// ---------------- conv2 v5: B-slice staged in LDS (4x L2-traffic cut) --------------
// Per-kt weight slice (18,432 B) in LDS, single-buffered: staged cooperatively,
// issued early into regs at end of iter k-1, written after the post-MFMA barrier.
// LDS = 46,080 (data ring) + 18,432 (B) = 64,512 B -> 2 blocks/CU.
__global__ __launch_bounds__(256) void conv2_kernel(
    const unsigned short* __restrict__ c1out, const unsigned short* __restrict__ wt2,
    const float* __restrict__ b2, unsigned short* __restrict__ X2) {
  __shared__ __align__(16) int ldsA[8 * 360 * 4];   // 46,080 B data ring
  __shared__ __align__(16) int ldsB[4608];          // 18,432 B weight slice (one kt)
  int tid = threadIdx.x;
  int lane = tid & 63, wave = tid >> 6;
  int quad = lane >> 4, l16 = lane & 15;
  int j = blockIdx.x;       // 0..14
  int b = blockIdx.y;       // 0..63

  int tlA[4], baseA[4];
#pragma unroll
  for (int mt = 0; mt < 4; ++mt) {
    int ml = wave * 64 + mt * 16 + l16;
    if (ml > 251) ml = 251;
    int tl = ml / 36;
    int f2 = ml - tl * 36;
    tlA[mt] = tl;
    baseA[mt] = (9 * f2 + quad) * 4;
  }

  f32x4 zero = {0.f, 0.f, 0.f, 0.f};
  f32x4 acc[4][2];
#pragma unroll
  for (int mt = 0; mt < 4; ++mt) {
    acc[mt][0] = zero;
    acc[mt][1] = zero;
  }

  const size_t rowsh = 2560;  // shorts per t-row (80*32)
  const unsigned short* gbase = c1out + ((size_t)b * 241 + 14 * j) * rowsh;
  int ra = tid;
  int rb = (tid < 64) ? 256 + tid : 319;   // uniform 2 loads/thread (dup clamped)
  int bc4 = (tid < 128) ? 1024 + tid : 1151;  // 5th B chunk (dup clamped)
  const unsigned short* bkl = (const unsigned short*)ldsB + l16 * 32 + quad * 8;

  for (int p = 0; p < 2; ++p) {
    // ---- prologue: data slots 0..6 + B slice kt=p, synchronous ----
#pragma unroll
    for (int k = 0; k < 9; ++k) {
      int i = tid + 256 * k;
      if (i < 2240) {
        int h = i / 320, r = i - 320 * h;
        int4 v = *(const int4*)(gbase + (size_t)(p + 2 * h) * rowsh + r * 8);
        *((int4*)&ldsA[(h * 360 + r + (r >> 3)) * 4]) = v;
      }
    }
    {
      const int4* bs = (const int4*)(wt2 + (size_t)p * 9216);
#pragma unroll
      for (int i = 0; i < 4; ++i) {
        int4 v = bs[tid + 256 * i];
        *((int4*)&ldsB[(tid + 256 * i) * 4]) = v;
      }
      if (tid < 128) {
        int4 v = bs[1024 + tid];
        *((int4*)&ldsB[(1024 + tid) * 4]) = v;
      }
    }
    asm volatile("" ::: "memory");
    // ---- issue data row h=7 + B slice kt=p+2; in flight across barriers ----
    const unsigned short* g7 = gbase + (size_t)(p + 14) * rowsh;
    int4 La = *(const int4*)(g7 + ra * 8);
    int4 Lb = *(const int4*)(g7 + rb * 8);
    const int4* bsn = (const int4*)(wt2 + (size_t)(p + 2) * 9216);
    int4 Bv0 = bsn[tid];
    int4 Bv1 = bsn[tid + 256];
    int4 Bv2 = bsn[tid + 512];
    int4 Bv3 = bsn[tid + 768];
    int4 Bv4 = bsn[bc4];
    asm volatile("" ::: "memory");
    barL();

    for (int k = 0; k < 16; ++k) {
      // ---- MFMA phase: A from ring slots, B from LDS slice ----
#pragma unroll
      for (int kf = 0; kf < 9; ++kf) {
        s16x8 b0 = *(const s16x8*)(bkl + kf * 1024);
        s16x8 b1v = *(const s16x8*)(bkl + kf * 1024 + 512);
        int kfo = (4 * kf + (kf >> 1)) * 4;
#pragma unroll
        for (int mt = 0; mt < 4; ++mt) {
          int slot = (k + tlA[mt]) & 7;
          s16x8 a = *(const s16x8*)&ldsA[slot * 1440 + baseA[mt] + kfo];
          acc[mt][0] = __builtin_amdgcn_mfma_f32_16x16x32_bf16(a, b0, acc[mt][0], 0, 0, 0);
          acc[mt][1] = __builtin_amdgcn_mfma_f32_16x16x32_bf16(a, b1v, acc[mt][1], 0, 0, 0);
        }
      }
      barL();   // all reads of slice kt / slots {k..k+6} complete
      if (k < 15) {
        asm volatile("s_waitcnt vmcnt(0)" ::: "memory");
        // write-late: data row p+2(k+7) -> slot (k+7)&7; B slice 2(k+1)+p
        int slot = (k + 7) & 7;
        *((int4*)&ldsA[(slot * 360 + ra + (ra >> 3)) * 4]) = La;
        if (tid < 64) *((int4*)&ldsA[(slot * 360 + rb + (rb >> 3)) * 4]) = Lb;
        *((int4*)&ldsB[tid * 4]) = Bv0;
        *((int4*)&ldsB[(tid + 256) * 4]) = Bv1;
        *((int4*)&ldsB[(tid + 512) * 4]) = Bv2;
        *((int4*)&ldsB[(tid + 768) * 4]) = Bv3;
        if (tid < 128) *((int4*)&ldsB[(1024 + tid) * 4]) = Bv4;
        if (k <= 13) {
          // issue-early for iter k+2: data row p+2(k+8), B slice 2(k+2)+p
          const unsigned short* gn = gbase + (size_t)(p + 2 * (k + 8)) * rowsh;
          La = *(const int4*)(gn + ra * 8);
          Lb = *(const int4*)(gn + rb * 8);
          const int4* bs2 = (const int4*)(wt2 + (size_t)(2 * (k + 2) + p) * 9216);
          Bv0 = bs2[tid];
          Bv1 = bs2[tid + 256];
          Bv2 = bs2[tid + 512];
          Bv3 = bs2[tid + 768];
          Bv4 = bs2[bc4];
        }
        asm volatile("" ::: "memory");
        barL();  // staged data visible before next MFMA phase
      }
    }
  }

#pragma unroll
  for (int nt = 0; nt < 2; ++nt) {
    int n = nt * 16 + l16;
    float bias = b2[n];
#pragma unroll
    for (int mt = 0; mt < 4; ++mt) {
      f32x4 v = acc[mt][nt];
#pragma unroll
      for (int r = 0; r < 4; ++r) {
        int ml = wave * 64 + mt * 16 + quad * 4 + r;
        if (ml < 252) {
          int tl = ml / 36;
          int f2 = ml - tl * 36;
          int t2 = 7 * j + tl;
          float val = v[r] + bias;
          val = val > 0.0f ? val : 0.0f;
          X2[((size_t)(b * 105 + t2) * 32 + n) * 36 + f2] = f2b(val);
        }
      }
    }
  }
}

// ---------------- xp GEMM: xp[(b,t2)][j] = X2 @ w_ih^T + b_ih, M=6720,N=384,K=1152 ---
__global__ __launch_bounds__(256) void xp_kernel(
    const unsigned short* __restrict__ X2, const unsigned short* __restrict__ wihB,
    const float* __restrict__ bih, float* __restrict__ xp) {
  int tid = threadIdx.x;
  int lane = tid & 63, wave = tid >> 6;
  int quad = lane >> 4, l16 = lane & 15;
  int m_tile = blockIdx.x * 4 + wave;   // 0..419
  int n0 = blockIdx.y * 128;
  int row = m_tile * 16 + l16;
  const unsigned short* apb = X2 + (size_t)row * 1152 + quad * 8;
  const unsigned short* bpb = wihB + (size_t)(n0 + l16) * 1152 + quad * 8;
  f32x4 zero = {0.f, 0.f, 0.f, 0.f};
  f32x4 acc[8];
#pragma unroll
  for (int nt = 0; nt < 8; ++nt) acc[nt] = zero;
  for (int ks = 0; ks < 36; ++ks) {
    s16x8 a = *(const s16x8*)(apb + ks * 32);
#pragma unroll
    for (int nt = 0; nt < 8; ++nt) {
      s16x8 bb = *(const s16x8*)(bpb + (size_t)nt * 16 * 1152 + ks * 32);
      acc[nt] = __builtin_amdgcn_mfma_f32_16x16x32_bf16(a, bb, acc[nt], 0, 0, 0);
    }
  }
#pragma unroll
  for (int nt = 0; nt < 8; ++nt) {
    int n = n0 + nt * 16 + l16;
    float bias = bih[n];
#pragma unroll
    for (int r = 0; r < 4; ++r) {
      int m = m_tile * 16 + quad * 4 + r;
      xp[(size_t)m * 384 + n] = acc[nt][r] + bias;
    }
  }
}

// ---------------- ip: emb[y] @ dec_w_ih^T + b ---------------------------------------
__global__ __launch_bounds__(384) void ip_kernel(
    const int* __restrict__ y, const float* __restrict__ emb,
    const float* __restrict__ wdT, const float* __restrict__ dbih,
    float* __restrict__ ipg) {
  __shared__ float er[32];
  int bs = blockIdx.x;
  int b = bs / 63, s = bs - b * 63;
  int tid = threadIdx.x;
  if (tid < 32) er[tid] = emb[(size_t)y[b * 64 + s] * 32 + tid];
  __syncthreads();
  float acc = dbih[tid];
#pragma unroll
  for (int e = 0; e < 32; ++e) acc = fmaf(er[e], wdT[e * 384 + tid], acc);
  ipg[(size_t)bs * 384 + tid] = acc;
}

// ---------------- fused RNN: encoder (105) + attention decoder (63), 64 blocks ------
// v4: all hot dot-product loops in packed f32x4 fma (v_pk_fma_f32, 2 FMA/instr)
// to halve VALU issue on the double-loaded SIMDs (6 waves over 4 SIMDs).
// Barriers lgkm-only; softmax max-free (bounded scores); fc pipelined one step.
__global__ __launch_bounds__(384) void rnn_kernel(
    const float* __restrict__ xp, const unsigned int* __restrict__ wpe,
    const float* __restrict__ bhh, const float* __restrict__ ipg,
    const unsigned int* __restrict__ wpd, const float* __restrict__ dbhh,
    const float* __restrict__ fcw, const float* __restrict__ fcb,
    float* __restrict__ outg) {
  __shared__ __align__(16) float ehT[128 * 116];   // 59,392 B  (ctx reads rows)
  __shared__ __align__(16) float ehR[105 * 132];   // 55,440 B  (score reads rows)
  __shared__ __align__(16) float gh_s[384];
  __shared__ __align__(16) float h_s[128];
  __shared__ __align__(16) float hx2_s[128];
  __shared__ __align__(16) float a_s[112];
  __shared__ float red_s[1];
  int tid = threadIdx.x, b = blockIdx.x;

  // ================= encoder =================
  f32x4 wq[32];
#pragma unroll
  for (int q = 0; q < 32; ++q) {
    unsigned int w0 = wpe[(2 * q) * 384 + tid];
    unsigned int w1 = wpe[(2 * q + 1) * 384 + tid];
    f32x4 t = {blo(w0), bhi(w0), blo(w1), bhi(w1)};
    wq[q] = t;
  }
  float bias = bhh[tid];
  if (tid < 128) h_s[tid] = 0.0f;
  if (tid < 112) a_s[tid] = 0.0f;            // pad cols 105..111 stay 0 forever
  for (int i = tid; i < 128 * 11; i += 384) { // zero ehT pad t=105..115
    int d = i / 11, t = 105 + i - (i / 11) * 11;
    ehT[d * 116 + t] = 0.0f;
  }
  barL();

  const float* xpb = xp + (size_t)b * 105 * 384;
  float nxg = (tid < 256) ? xpb[tid] : 0.0f;
  float nxn = (tid < 128) ? xpb[tid + 256] : 0.0f;
  for (int t = 0; t < 105; ++t) {
    float cxg = nxg, cxn = nxn;
    if (t < 104) {
      const float* xpt = xpb + (size_t)(t + 1) * 384;
      nxg = (tid < 256) ? xpt[tid] : 0.0f;
      nxn = (tid < 128) ? xpt[tid + 256] : 0.0f;
    }
    f32x4 accA = {bias, 0.f, 0.f, 0.f};
    f32x4 accB = {0.f, 0.f, 0.f, 0.f};
#pragma unroll
    for (int q = 0; q < 32; q += 2) {
      f32x4 hA = *(const f32x4*)&h_s[4 * q];
      f32x4 hB = *(const f32x4*)&h_s[4 * q + 4];
      accA = __builtin_elementwise_fma(hA, wq[q], accA);
      accB = __builtin_elementwise_fma(hB, wq[q + 1], accB);
    }
    float acc = ((accA.x + accA.y) + (accA.z + accA.w)) +
                ((accB.x + accB.y) + (accB.z + accB.w));
    gh_s[tid] = (tid < 256) ? sigmoidf_(cxg + acc) : acc;
    barL();
    if (tid < 128) {
      float r = gh_s[tid], z = gh_s[tid + 128], hnp = gh_s[tid + 256];
      float nn = tanhf_(cxn + r * hnp);
      float hn = (1.0f - z) * nn + z * h_s[tid];
      h_s[tid] = hn;
      ehT[tid * 116 + t] = hn;
      ehR[t * 132 + tid] = hn;
    }
    barL();
  }

  // ================= decoder =================
#pragma unroll
  for (int q = 0; q < 32; ++q) {
    unsigned int w0 = wpd[(2 * q) * 384 + tid];
    unsigned int w1 = wpd[(2 * q + 1) * 384 + tid];
    f32x4 t = {blo(w0), bhi(w0), blo(w1), bhi(w1)};
    wq[q] = t;
  }
  bias = dbhh[tid];
  f32x4 wf4[8];
  float fcbv = 0.0f;
  int fv = 0, fp = 0;
  if (tid >= 256) {
    int i = tid - 256;
    fp = i & 3; fv = i >> 2;
#pragma unroll
    for (int d = 0; d < 8; ++d) wf4[d] = *(const f32x4*)&fcw[fv * 128 + fp * 32 + 4 * d];
    fcbv = fcb[fv];
  }
  if (tid < 128) h_s[tid] = 0.0f;
  if (tid == 0) red_s[0] = 1.0f;             // h_s is unnormalized ctx; rsum=1 at s=0
  barL();

  const float* ipb = ipg + (size_t)b * 63 * 384;
  nxg = (tid < 256) ? ipb[tid] : 0.0f;
  nxn = (tid < 128) ? ipb[tid + 256] : 0.0f;
  for (int s = 0; s < 63; ++s) {
    float cxg = nxg, cxn = nxn;
    if (s < 62) {
      const float* ipt = ipb + (size_t)(s + 1) * 384;
      nxg = (tid < 256) ? ipt[tid] : 0.0f;
      nxn = (tid < 128) ? ipt[tid + 256] : 0.0f;
    }
    float rsum = red_s[0];                   // norm factor for h_s (prev step's ctx)
    // ---- (A) GEMV over unnormalized ctx; scale folded in at the end ----
    f32x4 accA = {0.f, 0.f, 0.f, 0.f};
    f32x4 accB = {0.f, 0.f, 0.f, 0.f};
#pragma unroll
    for (int q = 0; q < 32; q += 2) {
      f32x4 hA = *(const f32x4*)&h_s[4 * q];
      f32x4 hB = *(const f32x4*)&h_s[4 * q + 4];
      accA = __builtin_elementwise_fma(hA, wq[q], accA);
      accB = __builtin_elementwise_fma(hB, wq[q + 1], accB);
    }
    float dot = ((accA.x + accA.y) + (accA.z + accA.w)) +
                ((accB.x + accB.y) + (accB.z + accB.w));
    float acc = fmaf(rsum, dot, bias);
    gh_s[tid] = (tid < 256) ? sigmoidf_(cxg + acc) : acc;
    barL();                              // (1) gh ready
    if (tid < 128) {
      float r = gh_s[tid], z = gh_s[tid + 128], hnp = gh_s[tid + 256];
      float nn = tanhf_(cxn + r * hnp);
      hx2_s[tid] = (1.0f - z) * nn + z * (rsum * h_s[tid]);
    }
    barL();                              // (2) hx2 ready

    // ---- (B) scores -> exp directly (no max; bounded), fc(prev) on waves 4-5 ----
    if (tid < 256) {
      int row = tid >> 1; if (row > 104) row = 104;
      int part = tid & 1;
      const float* erow = &ehR[row * 132 + part * 64];
      const float* hp = &hx2_s[part * 64];
      f32x4 sv = {0.f, 0.f, 0.f, 0.f};
#pragma unroll
      for (int jj = 0; jj < 16; ++jj) {
        f32x4 e4 = *(const f32x4*)&erow[4 * jj];
        f32x4 h4 = *(const f32x4*)&hp[4 * jj];
        sv = __builtin_elementwise_fma(e4, h4, sv);
      }
      float sc = (sv.x + sv.y) + (sv.z + sv.w);
      sc += __shfl_xor(sc, 1);           // both halves now hold the full dot
      if (part == 0 && tid < 210) a_s[row] = __expf(fminf(sc, 75.0f));
    } else if (s > 0) {
      // fc for PREVIOUS step: h_s still holds prev unnormalized ctx; rsum = prev norm
      const f32x4* cx = (const f32x4*)&h_s[fp * 32];
      f32x4 pv = {0.f, 0.f, 0.f, 0.f};
#pragma unroll
      for (int d = 0; d < 8; ++d) pv = __builtin_elementwise_fma(cx[d], wf4[d], pv);
      float p = (pv.x + pv.z) + (pv.y + pv.w);
      p += __shfl_xor(p, 1);
      p += __shfl_xor(p, 2);
      if (fp == 0) outg[((size_t)b * 63 + (s - 1)) * 32 + fv] = fmaf(p, rsum, fcbv);
    }
    barL();                              // (3) a_s ready

    // ---- (C) ctx (unnormalized, waves 0-3) || sum-reduce (wave 4, concurrent) ----
    if (tid < 256) {
      int d = tid >> 1, half = tid & 1;
      const float* erow = &ehT[d * 116 + half * 56];
      const float* ap = &a_s[half * 56];
      f32x4 cv = {0.f, 0.f, 0.f, 0.f};
#pragma unroll
      for (int jj = 0; jj < 14; ++jj) {
        f32x4 e4 = *(const f32x4*)&erow[4 * jj];
        f32x4 a4 = *(const f32x4*)&ap[4 * jj];
        cv = __builtin_elementwise_fma(e4, a4, cv);
      }
      float c = (cv.x + cv.y) + (cv.z + cv.w);
      c += __shfl_xor(c, 1);
      if (half == 0) h_s[d] = c;         // carry = UNNORMALIZED ctx
    } else if (tid < 320) {
      int l = tid - 256;
      float sv = a_s[l] + ((l < 48) ? a_s[64 + l] : 0.0f);  // pads 105..111 are 0
      sv += __shfl_xor(sv, 1);
      sv += __shfl_xor(sv, 2);
      sv += __shfl_xor(sv, 4);
      sv += __shfl_xor(sv, 8);
      sv += __shfl_xor(sv, 16);
      sv += __shfl_xor(sv, 32);
      if (l == 0) red_s[0] = 1.0f / sv;
    }
    barL();                              // (4) ctx_u + rsum ready
  }

  // final fc (s=62): h_s = ctx62 (unnormalized), red_s = its norm
  if (tid >= 256) {
    float rs = red_s[0];
    const f32x4* cx = (const f32x4*)&h_s[fp * 32];
    f32x4 pv = {0.f, 0.f, 0.f, 0.f};
#pragma unroll
    for (int d = 0; d < 8; ++d) pv = __builtin_elementwise_fma(cx[d], wf4[d], pv);
    float p = (pv.x + pv.z) + (pv.y + pv.w);
    p += __shfl_xor(p, 1);
    p += __shfl_xor(p, 2);
    if (fp == 0) outg[((size_t)b * 63 + 62) * 32 + fv] = fmaf(p, rs, fcbv);
  }
}

extern "C" void kernel_launch(void* const* d_in, const int* in_sizes, int n_in,
                              void* d_out, int out_size, void* d_ws, size_t ws_size,
                              hipStream_t stream) {
  const float* x = (const float*)d_in[0];
  const int* y = (const int*)d_in[1];
  const float* mean = (const float*)d_in[2];
  const float* stdv = (const float*)d_in[3];
  const float* w1 = (const float*)d_in[4];
  const float* b1 = (const float*)d_in[5];
  const float* w2 = (const float*)d_in[6];
  const float* b2 = (const float*)d_in[7];
  const float* wih = (const float*)d_in[8];
  const float* whh = (const float*)d_in[9];
  const float* bih = (const float*)d_in[10];
  const float* bhh = (const float*)d_in[11];
  const float* emb = (const float*)d_in[12];
  const float* dwih = (const float*)d_in[13];
  const float* dwhh = (const float*)d_in[14];
  const float* dbih = (const float*)d_in[15];
  const float* dbhh = (const float*)d_in[16];
  const float* fcw = (const float*)d_in[17];
  const float* fcb = (const float*)d_in[18];
  float* out = (float*)d_out;
  char* ws = (char*)d_ws;

  // ws layout (bytes); xp/ip overlap dead c1out region (both written after conv2).
  unsigned short* c1out = (unsigned short*)(ws + 0);              // 78,970,880 B
  float* xp = (float*)(ws + 0);                                   // 10,321,920 B (after conv2)
  float* ipg = (float*)(ws + 13762560);                           //  6,193,152 B
  unsigned short* wt2 = (unsigned short*)(ws + 78970880);         //    589,824 B
  unsigned short* wihB = (unsigned short*)(ws + 79560704);        //    884,736 B
  unsigned int* wpe = (unsigned int*)(ws + 80445440);             //     98,304 B
  unsigned int* wpd = (unsigned int*)(ws + 80543744);             //     98,304 B
  float* wdT = (float*)(ws + 80642048);                           //     49,152 B
  unsigned short* X2 = (unsigned short*)(ws + 80691200);          // 15,482,880 B

  prep_kernel<<<3120, 256, 0, stream>>>(w2, wih, whh, dwhh, dwih, wt2, wihB, wpe, wpd, wdT);
  conv1_kernel<<<dim3(31, 64), 256, 0, stream>>>(x, mean, stdv, w1, b1, c1out);
  conv2_kernel<<<dim3(15, 64), 256, 0, stream>>>(c1out, wt2, b2, X2);
  xp_kernel<<<dim3(105, 3), 256, 0, stream>>>(X2, wihB, bih, xp);
  ip_kernel<<<64 * 63, 384, 0, stream>>>(y, emb, wdT, dbih, ipg);
  rnn_kernel<<<64, 384, 0, stream>>>(xp, wpe, bhh, ipg, wpd, dbhh, fcw, fcb, out);
}

// Round 6
// 649.534 us; speedup vs baseline: 1.4859x; 1.4859x over previous
//
#include <hip/hip_runtime.h>

// Model: conv(32x2,s2) -> conv(32x9,s2) -> GRU encoder (105 steps) ->
//        attention decoder (63 steps) -> fc.  B=64,H=128,V=32.

typedef float f32x4 __attribute__((ext_vector_type(4)));
typedef short s16x8 __attribute__((ext_vector_type(8)));

static __device__ __forceinline__ unsigned short f2b(float f) {
  unsigned int u = __float_as_uint(f);
  unsigned int r = u + 0x7fffu + ((u >> 16) & 1u);
  return (unsigned short)(r >> 16);
}
static __device__ __forceinline__ float sigmoidf_(float x) {
  return 1.0f / (1.0f + __expf(-x));
}
static __device__ __forceinline__ float tanhf_(float x) {
  float ax = fabsf(x);
  float t = __expf(-2.0f * ax);
  float r = (1.0f - t) / (1.0f + t);
  return x >= 0.0f ? r : -r;
}
static __device__ __forceinline__ float blo(unsigned int w) {
  return __uint_as_float(w << 16);
}
static __device__ __forceinline__ float bhi(unsigned int w) {
  return __uint_as_float(w & 0xffff0000u);
}
// lgkmcnt-only barrier: does NOT drain vmcnt, so global prefetch loads stay
// in flight across phase barriers (only LDS ordering is needed).
static __device__ __forceinline__ void barL() {
  asm volatile("s_waitcnt lgkmcnt(0)" ::: "memory");
  __builtin_amdgcn_s_barrier();
  asm volatile("" ::: "memory");
}

// ---------------- weight pre-transforms (re-run every launch; ws is re-poisoned) ----
__global__ __launch_bounds__(256) void prep_kernel(
    const float* __restrict__ w2, const float* __restrict__ wih,
    const float* __restrict__ whh, const float* __restrict__ dwhh,
    const float* __restrict__ dwih,
    unsigned short* __restrict__ wt2, unsigned short* __restrict__ wihB,
    unsigned int* __restrict__ wpe, unsigned int* __restrict__ wpd,
    float* __restrict__ wdT) {
  int idx = blockIdx.x * 256 + threadIdx.x;
  if (idx < 294912) {
    int ci = idx & 31;
    int n = (idx >> 5) & 31;
    int kk = idx >> 10;          // kt*9+kf
    int kf = kk % 9, kt = kk / 9;
    wt2[idx] = f2b(w2[((n * 32 + ci) * 32 + kt) * 9 + kf]);
  } else if (idx < 737280) {
    int i = idx - 294912;
    wihB[i] = f2b(wih[i]);
  } else if (idx < 761856) {
    int i = idx - 737280;
    int j = i % 384, k2 = i / 384;
    unsigned int lo = f2b(whh[j * 128 + 2 * k2]);
    unsigned int hi = f2b(whh[j * 128 + 2 * k2 + 1]);
    wpe[i] = lo | (hi << 16);
  } else if (idx < 786432) {
    int i = idx - 761856;
    int j = i % 384, k2 = i / 384;
    unsigned int lo = f2b(dwhh[j * 128 + 2 * k2]);
    unsigned int hi = f2b(dwhh[j * 128 + 2 * k2 + 1]);
    wpd[i] = lo | (hi << 16);
  } else if (idx < 798720) {
    int i = idx - 786432;
    int j = i % 384, e = i / 384;
    wdT[i] = dwih[j * 32 + e];
  }
}

// ---------------- conv1 v4: one channel/thread compute + v2's 4B packed stores -----
// v3 lesson (r5): 2B/lane stores caused 8x HBM write amplification (614 MB) and
// an L3 eviction storm (FETCH 299 MB) -> 457us.  v4 keeps v3's register diet
// (64 weight VGPRs -> ~5 waves/SIMD, the real occupancy win) but packs channel
// pairs via __shfl_xor so even-c lanes issue the SAME 4B u32 store pattern v2
// used (16 lanes x 4B = full 64B lines).  fmaf order identical -> bitwise-same.
__global__ __launch_bounds__(256) void conv1_kernel(
    const float* __restrict__ x, const float* __restrict__ mean,
    const float* __restrict__ stdv, const float* __restrict__ w1,
    const float* __restrict__ b1, unsigned short* __restrict__ c1out) {
  __shared__ float ins[46][162];
  __shared__ float meanL[161];
  __shared__ float rstdL[161];
  int tid = threadIdx.x;
  int tt = blockIdx.x;        // 0..30
  int b = blockIdx.y;         // 0..63
  int t0 = tt * 8;
  if (tid < 161) {
    meanL[tid] = mean[tid];
    rstdL[tid] = 1.0f / stdv[tid];
  }
  int c = tid & 31, fs = tid >> 5;   // one channel, 8 f-groups
  float w[64];
  {
    const float4* wp = (const float4*)(w1 + c * 64);
#pragma unroll
    for (int i = 0; i < 16; ++i) {
      float4 v = wp[i];
      w[4 * i] = v.x; w[4 * i + 1] = v.y; w[4 * i + 2] = v.z; w[4 * i + 3] = v.w;
    }
  }
  float bias = b1[c];
  __syncthreads();   // meanL/rstdL ready

  const float* xb = x + ((size_t)b * 512 + 2 * t0) * 161;
  int nrows = 512 - 2 * t0; if (nrows > 46) nrows = 46;
  for (int i = tid; i < 46 * 161; i += 256) {
    int r = i / 161, col = i - r * 161;
    float v = (r < nrows) ? xb[(size_t)r * 161 + col] : 0.0f;
    ins[r][col] = (v - meanL[col]) * rstdL[col];
  }
  __syncthreads();

  int T = 241 - t0; if (T > 8) T = 8;
#pragma unroll
  for (int fi = 0; fi < 10; ++fi) {
    int f = fs + 8 * fi;
    float acc[8];
#pragma unroll
    for (int t = 0; t < 8; ++t) acc[t] = bias;
#pragma unroll
    for (int r = 0; r < 46; ++r) {
      float2 v = *(const float2*)&ins[r][2 * f];
#pragma unroll
      for (int t = 0; t < 8; ++t) {
        const int kt = r - 2 * t;
        if (kt >= 0 && kt < 32) {
          acc[t] = fmaf(v.x, w[2 * kt], acc[t]);
          acc[t] = fmaf(v.y, w[2 * kt + 1], acc[t]);
        }
      }
    }
#pragma unroll
    for (int t = 0; t < 8; ++t) {
      if (t < T) {
        float a = acc[t] > 0.0f ? acc[t] : 0.0f;
        unsigned int h = (unsigned int)f2b(a);
        unsigned int o = __shfl_xor(h, 1);   // neighbor channel's bf16
        if (!(c & 1)) {
          unsigned int pk = h | (o << 16);
          *(unsigned int*)&c1out[(((size_t)b * 241 + t0 + t) * 80 + f) * 32 + c] = pk;
        }
      }
    }
  }
}

// ---------------- conv2 v5: B-slice staged in LDS (4x L2-traffic cut) --------------
// Per-kt weight slice (18,432 B) in LDS, single-buffered: staged cooperatively,
// issued early into regs at end of iter k-1, written after the post-MFMA barrier.
// LDS = 46,080 (data ring) + 18,432 (B) = 64,512 B -> 2 blocks/CU.
__global__ __launch_bounds__(256) void conv2_kernel(
    const unsigned short* __restrict__ c1out, const unsigned short* __restrict__ wt2,
    const float* __restrict__ b2, unsigned short* __restrict__ X2) {
  __shared__ __align__(16) int ldsA[8 * 360 * 4];   // 46,080 B data ring
  __shared__ __align__(16) int ldsB[4608];          // 18,432 B weight slice (one kt)
  int tid = threadIdx.x;
  int lane = tid & 63, wave = tid >> 6;
  int quad = lane >> 4, l16 = lane & 15;
  int j = blockIdx.x;       // 0..14
  int b = blockIdx.y;       // 0..63

  int tlA[4], baseA[4];
#pragma unroll
  for (int mt = 0; mt < 4; ++mt) {
    int ml = wave * 64 + mt * 16 + l16;
    if (ml > 251) ml = 251;
    int tl = ml / 36;
    int f2 = ml - tl * 36;
    tlA[mt] = tl;
    baseA[mt] = (9 * f2 + quad) * 4;
  }

  f32x4 zero = {0.f, 0.f, 0.f, 0.f};
  f32x4 acc[4][2];
#pragma unroll
  for (int mt = 0; mt < 4; ++mt) {
    acc[mt][0] = zero;
    acc[mt][1] = zero;
  }

  const size_t rowsh = 2560;  // shorts per t-row (80*32)
  const unsigned short* gbase = c1out + ((size_t)b * 241 + 14 * j) * rowsh;
  int ra = tid;
  int rb = (tid < 64) ? 256 + tid : 319;   // uniform 2 loads/thread (dup clamped)
  int bc4 = (tid < 128) ? 1024 + tid : 1151;  // 5th B chunk (dup clamped)
  const unsigned short* bkl = (const unsigned short*)ldsB + l16 * 32 + quad * 8;

  for (int p = 0; p < 2; ++p) {
    // ---- prologue: data slots 0..6 + B slice kt=p, synchronous ----
#pragma unroll
    for (int k = 0; k < 9; ++k) {
      int i = tid + 256 * k;
      if (i < 2240) {
        int h = i / 320, r = i - 320 * h;
        int4 v = *(const int4*)(gbase + (size_t)(p + 2 * h) * rowsh + r * 8);
        *((int4*)&ldsA[(h * 360 + r + (r >> 3)) * 4]) = v;
      }
    }
    {
      const int4* bs = (const int4*)(wt2 + (size_t)p * 9216);
#pragma unroll
      for (int i = 0; i < 4; ++i) {
        int4 v = bs[tid + 256 * i];
        *((int4*)&ldsB[(tid + 256 * i) * 4]) = v;
      }
      if (tid < 128) {
        int4 v = bs[1024 + tid];
        *((int4*)&ldsB[(1024 + tid) * 4]) = v;
      }
    }
    asm volatile("" ::: "memory");
    // ---- issue data row h=7 + B slice kt=p+2; in flight across barriers ----
    const unsigned short* g7 = gbase + (size_t)(p + 14) * rowsh;
    int4 La = *(const int4*)(g7 + ra * 8);
    int4 Lb = *(const int4*)(g7 + rb * 8);
    const int4* bsn = (const int4*)(wt2 + (size_t)(p + 2) * 9216);
    int4 Bv0 = bsn[tid];
    int4 Bv1 = bsn[tid + 256];
    int4 Bv2 = bsn[tid + 512];
    int4 Bv3 = bsn[tid + 768];
    int4 Bv4 = bsn[bc4];
    asm volatile("" ::: "memory");
    barL();

    for (int k = 0; k < 16; ++k) {
      // ---- MFMA phase: A from ring slots, B from LDS slice ----
#pragma unroll
      for (int kf = 0; kf < 9; ++kf) {
        s16x8 b0 = *(const s16x8*)(bkl + kf * 1024);
        s16x8 b1v = *(const s16x8*)(bkl + kf * 1024 + 512);
        int kfo = (4 * kf + (kf >> 1)) * 4;
#pragma unroll
        for (int mt = 0; mt < 4; ++mt) {
          int slot = (k + tlA[mt]) & 7;
          s16x8 a = *(const s16x8*)&ldsA[slot * 1440 + baseA[mt] + kfo];
          acc[mt][0] = __builtin_amdgcn_mfma_f32_16x16x32_bf16(a, b0, acc[mt][0], 0, 0, 0);
          acc[mt][1] = __builtin_amdgcn_mfma_f32_16x16x32_bf16(a, b1v, acc[mt][1], 0, 0, 0);
        }
      }
      barL();   // all reads of slice kt / slots {k..k+6} complete
      if (k < 15) {
        asm volatile("s_waitcnt vmcnt(0)" ::: "memory");
        // write-late: data row p+2(k+7) -> slot (k+7)&7; B slice 2(k+1)+p
        int slot = (k + 7) & 7;
        *((int4*)&ldsA[(slot * 360 + ra + (ra >> 3)) * 4]) = La;
        if (tid < 64) *((int4*)&ldsA[(slot * 360 + rb + (rb >> 3)) * 4]) = Lb;
        *((int4*)&ldsB[tid * 4]) = Bv0;
        *((int4*)&ldsB[(tid + 256) * 4]) = Bv1;
        *((int4*)&ldsB[(tid + 512) * 4]) = Bv2;
        *((int4*)&ldsB[(tid + 768) * 4]) = Bv3;
        if (tid < 128) *((int4*)&ldsB[(1024 + tid) * 4]) = Bv4;
        if (k <= 13) {
          // issue-early for iter k+2: data row p+2(k+8), B slice 2(k+2)+p
          const unsigned short* gn = gbase + (size_t)(p + 2 * (k + 8)) * rowsh;
          La = *(const int4*)(gn + ra * 8);
          Lb = *(const int4*)(gn + rb * 8);
          const int4* bs2 = (const int4*)(wt2 + (size_t)(2 * (k + 2) + p) * 9216);
          Bv0 = bs2[tid];
          Bv1 = bs2[tid + 256];
          Bv2 = bs2[tid + 512];
          Bv3 = bs2[tid + 768];
          Bv4 = bs2[bc4];
        }
        asm volatile("" ::: "memory");
        barL();  // staged data visible before next MFMA phase
      }
    }
  }

#pragma unroll
  for (int nt = 0; nt < 2; ++nt) {
    int n = nt * 16 + l16;
    float bias = b2[n];
#pragma unroll
    for (int mt = 0; mt < 4; ++mt) {
      f32x4 v = acc[mt][nt];
#pragma unroll
      for (int r = 0; r < 4; ++r) {
        int ml = wave * 64 + mt * 16 + quad * 4 + r;
        if (ml < 252) {
          int tl = ml / 36;
          int f2 = ml - tl * 36;
          int t2 = 7 * j + tl;
          float val = v[r] + bias;
          val = val > 0.0f ? val : 0.0f;
          X2[((size_t)(b * 105 + t2) * 32 + n) * 36 + f2] = f2b(val);
        }
      }
    }
  }
}

// ---------------- xp GEMM: xp[(b,t2)][j] = X2 @ w_ih^T + b_ih, M=6720,N=384,K=1152 ---
__global__ __launch_bounds__(256) void xp_kernel(
    const unsigned short* __restrict__ X2, const unsigned short* __restrict__ wihB,
    const float* __restrict__ bih, float* __restrict__ xp) {
  int tid = threadIdx.x;
  int lane = tid & 63, wave = tid >> 6;
  int quad = lane >> 4, l16 = lane & 15;
  int m_tile = blockIdx.x * 4 + wave;   // 0..419
  int n0 = blockIdx.y * 128;
  int row = m_tile * 16 + l16;
  const unsigned short* apb = X2 + (size_t)row * 1152 + quad * 8;
  const unsigned short* bpb = wihB + (size_t)(n0 + l16) * 1152 + quad * 8;
  f32x4 zero = {0.f, 0.f, 0.f, 0.f};
  f32x4 acc[8];
#pragma unroll
  for (int nt = 0; nt < 8; ++nt) acc[nt] = zero;
  for (int ks = 0; ks < 36; ++ks) {
    s16x8 a = *(const s16x8*)(apb + ks * 32);
#pragma unroll
    for (int nt = 0; nt < 8; ++nt) {
      s16x8 bb = *(const s16x8*)(bpb + (size_t)nt * 16 * 1152 + ks * 32);
      acc[nt] = __builtin_amdgcn_mfma_f32_16x16x32_bf16(a, bb, acc[nt], 0, 0, 0);
    }
  }
#pragma unroll
  for (int nt = 0; nt < 8; ++nt) {
    int n = n0 + nt * 16 + l16;
    float bias = bih[n];
#pragma unroll
    for (int r = 0; r < 4; ++r) {
      int m = m_tile * 16 + quad * 4 + r;
      xp[(size_t)m * 384 + n] = acc[nt][r] + bias;
    }
  }
}

// ---------------- ip: emb[y] @ dec_w_ih^T + b ---------------------------------------
__global__ __launch_bounds__(384) void ip_kernel(
    const int* __restrict__ y, const float* __restrict__ emb,
    const float* __restrict__ wdT, const float* __restrict__ dbih,
    float* __restrict__ ipg) {
  __shared__ float er[32];
  int bs = blockIdx.x;
  int b = bs / 63, s = bs - b * 63;
  int tid = threadIdx.x;
  if (tid < 32) er[tid] = emb[(size_t)y[b * 64 + s] * 32 + tid];
  __syncthreads();
  float acc = dbih[tid];
#pragma unroll
  for (int e = 0; e < 32; ++e) acc = fmaf(er[e], wdT[e * 384 + tid], acc);
  ipg[(size_t)bs * 384 + tid] = acc;
}

// ---------------- fused RNN: encoder (105) + attention decoder (63), 64 blocks ------
// v4: all hot dot-product loops in packed f32x4 fma (v_pk_fma_f32, 2 FMA/instr)
// to halve VALU issue on the double-loaded SIMDs (6 waves over 4 SIMDs).
// Barriers lgkm-only; softmax max-free (bounded scores); fc pipelined one step.
__global__ __launch_bounds__(384) void rnn_kernel(
    const float* __restrict__ xp, const unsigned int* __restrict__ wpe,
    const float* __restrict__ bhh, const float* __restrict__ ipg,
    const unsigned int* __restrict__ wpd, const float* __restrict__ dbhh,
    const float* __restrict__ fcw, const float* __restrict__ fcb,
    float* __restrict__ outg) {
  __shared__ __align__(16) float ehT[128 * 116];   // 59,392 B  (ctx reads rows)
  __shared__ __align__(16) float ehR[105 * 132];   // 55,440 B  (score reads rows)
  __shared__ __align__(16) float gh_s[384];
  __shared__ __align__(16) float h_s[128];
  __shared__ __align__(16) float hx2_s[128];
  __shared__ __align__(16) float a_s[112];
  __shared__ float red_s[1];
  int tid = threadIdx.x, b = blockIdx.x;

  // ================= encoder =================
  f32x4 wq[32];
#pragma unroll
  for (int q = 0; q < 32; ++q) {
    unsigned int w0 = wpe[(2 * q) * 384 + tid];
    unsigned int w1 = wpe[(2 * q + 1) * 384 + tid];
    f32x4 t = {blo(w0), bhi(w0), blo(w1), bhi(w1)};
    wq[q] = t;
  }
  float bias = bhh[tid];
  if (tid < 128) h_s[tid] = 0.0f;
  if (tid < 112) a_s[tid] = 0.0f;            // pad cols 105..111 stay 0 forever
  for (int i = tid; i < 128 * 11; i += 384) { // zero ehT pad t=105..115
    int d = i / 11, t = 105 + i - (i / 11) * 11;
    ehT[d * 116 + t] = 0.0f;
  }
  barL();

  const float* xpb = xp + (size_t)b * 105 * 384;
  float nxg = (tid < 256) ? xpb[tid] : 0.0f;
  float nxn = (tid < 128) ? xpb[tid + 256] : 0.0f;
  for (int t = 0; t < 105; ++t) {
    float cxg = nxg, cxn = nxn;
    if (t < 104) {
      const float* xpt = xpb + (size_t)(t + 1) * 384;
      nxg = (tid < 256) ? xpt[tid] : 0.0f;
      nxn = (tid < 128) ? xpt[tid + 256] : 0.0f;
    }
    f32x4 accA = {bias, 0.f, 0.f, 0.f};
    f32x4 accB = {0.f, 0.f, 0.f, 0.f};
#pragma unroll
    for (int q = 0; q < 32; q += 2) {
      f32x4 hA = *(const f32x4*)&h_s[4 * q];
      f32x4 hB = *(const f32x4*)&h_s[4 * q + 4];
      accA = __builtin_elementwise_fma(hA, wq[q], accA);
      accB = __builtin_elementwise_fma(hB, wq[q + 1], accB);
    }
    float acc = ((accA.x + accA.y) + (accA.z + accA.w)) +
                ((accB.x + accB.y) + (accB.z + accB.w));
    gh_s[tid] = (tid < 256) ? sigmoidf_(cxg + acc) : acc;
    barL();
    if (tid < 128) {
      float r = gh_s[tid], z = gh_s[tid + 128], hnp = gh_s[tid + 256];
      float nn = tanhf_(cxn + r * hnp);
      float hn = (1.0f - z) * nn + z * h_s[tid];
      h_s[tid] = hn;
      ehT[tid * 116 + t] = hn;
      ehR[t * 132 + tid] = hn;
    }
    barL();
  }

  // ================= decoder =================
#pragma unroll
  for (int q = 0; q < 32; ++q) {
    unsigned int w0 = wpd[(2 * q) * 384 + tid];
    unsigned int w1 = wpd[(2 * q + 1) * 384 + tid];
    f32x4 t = {blo(w0), bhi(w0), blo(w1), bhi(w1)};
    wq[q] = t;
  }
  bias = dbhh[tid];
  f32x4 wf4[8];
  float fcbv = 0.0f;
  int fv = 0, fp = 0;
  if (tid >= 256) {
    int i = tid - 256;
    fp = i & 3; fv = i >> 2;
#pragma unroll
    for (int d = 0; d < 8; ++d) wf4[d] = *(const f32x4*)&fcw[fv * 128 + fp * 32 + 4 * d];
    fcbv = fcb[fv];
  }
  if (tid < 128) h_s[tid] = 0.0f;
  if (tid == 0) red_s[0] = 1.0f;             // h_s is unnormalized ctx; rsum=1 at s=0
  barL();

  const float* ipb = ipg + (size_t)b * 63 * 384;
  nxg = (tid < 256) ? ipb[tid] : 0.0f;
  nxn = (tid < 128) ? ipb[tid + 256] : 0.0f;
  for (int s = 0; s < 63; ++s) {
    float cxg = nxg, cxn = nxn;
    if (s < 62) {
      const float* ipt = ipb + (size_t)(s + 1) * 384;
      nxg = (tid < 256) ? ipt[tid] : 0.0f;
      nxn = (tid < 128) ? ipt[tid + 256] : 0.0f;
    }
    float rsum = red_s[0];                   // norm factor for h_s (prev step's ctx)
    // ---- (A) GEMV over unnormalized ctx; scale folded in at the end ----
    f32x4 accA = {0.f, 0.f, 0.f, 0.f};
    f32x4 accB = {0.f, 0.f, 0.f, 0.f};
#pragma unroll
    for (int q = 0; q < 32; q += 2) {
      f32x4 hA = *(const f32x4*)&h_s[4 * q];
      f32x4 hB = *(const f32x4*)&h_s[4 * q + 4];
      accA = __builtin_elementwise_fma(hA, wq[q], accA);
      accB = __builtin_elementwise_fma(hB, wq[q + 1], accB);
    }
    float dot = ((accA.x + accA.y) + (accA.z + accA.w)) +
                ((accB.x + accB.y) + (accB.z + accB.w));
    float acc = fmaf(rsum, dot, bias);
    gh_s[tid] = (tid < 256) ? sigmoidf_(cxg + acc) : acc;
    barL();                              // (1) gh ready
    if (tid < 128) {
      float r = gh_s[tid], z = gh_s[tid + 128], hnp = gh_s[tid + 256];
      float nn = tanhf_(cxn + r * hnp);
      hx2_s[tid] = (1.0f - z) * nn + z * (rsum * h_s[tid]);
    }
    barL();                              // (2) hx2 ready

    // ---- (B) scores -> exp directly (no max; bounded), fc(prev) on waves 4-5 ----
    if (tid < 256) {
      int row = tid >> 1; if (row > 104) row = 104;
      int part = tid & 1;
      const float* erow = &ehR[row * 132 + part * 64];
      const float* hp = &hx2_s[part * 64];
      f32x4 sv = {0.f, 0.f, 0.f, 0.f};
#pragma unroll
      for (int jj = 0; jj < 16; ++jj) {
        f32x4 e4 = *(const f32x4*)&erow[4 * jj];
        f32x4 h4 = *(const f32x4*)&hp[4 * jj];
        sv = __builtin_elementwise_fma(e4, h4, sv);
      }
      float sc = (sv.x + sv.y) + (sv.z + sv.w);
      sc += __shfl_xor(sc, 1);           // both halves now hold the full dot
      if (part == 0 && tid < 210) a_s[row] = __expf(fminf(sc, 75.0f));
    } else if (s > 0) {
      // fc for PREVIOUS step: h_s still holds prev unnormalized ctx; rsum = prev norm
      const f32x4* cx = (const f32x4*)&h_s[fp * 32];
      f32x4 pv = {0.f, 0.f, 0.f, 0.f};
#pragma unroll
      for (int d = 0; d < 8; ++d) pv = __builtin_elementwise_fma(cx[d], wf4[d], pv);
      float p = (pv.x + pv.z) + (pv.y + pv.w);
      p += __shfl_xor(p, 1);
      p += __shfl_xor(p, 2);
      if (fp == 0) outg[((size_t)b * 63 + (s - 1)) * 32 + fv] = fmaf(p, rsum, fcbv);
    }
    barL();                              // (3) a_s ready

    // ---- (C) ctx (unnormalized, waves 0-3) || sum-reduce (wave 4, concurrent) ----
    if (tid < 256) {
      int d = tid >> 1, half = tid & 1;
      const float* erow = &ehT[d * 116 + half * 56];
      const float* ap = &a_s[half * 56];
      f32x4 cv = {0.f, 0.f, 0.f, 0.f};
#pragma unroll
      for (int jj = 0; jj < 14; ++jj) {
        f32x4 e4 = *(const f32x4*)&erow[4 * jj];
        f32x4 a4 = *(const f32x4*)&ap[4 * jj];
        cv = __builtin_elementwise_fma(e4, a4, cv);
      }
      float c = (cv.x + cv.y) + (cv.z + cv.w);
      c += __shfl_xor(c, 1);
      if (half == 0) h_s[d] = c;         // carry = UNNORMALIZED ctx
    } else if (tid < 320) {
      int l = tid - 256;
      float sv = a_s[l] + ((l < 48) ? a_s[64 + l] : 0.0f);  // pads 105..111 are 0
      sv += __shfl_xor(sv, 1);
      sv += __shfl_xor(sv, 2);
      sv += __shfl_xor(sv, 4);
      sv += __shfl_xor(sv, 8);
      sv += __shfl_xor(sv, 16);
      sv += __shfl_xor(sv, 32);
      if (l == 0) red_s[0] = 1.0f / sv;
    }
    barL();                              // (4) ctx_u + rsum ready
  }

  // final fc (s=62): h_s = ctx62 (unnormalized), red_s = its norm
  if (tid >= 256) {
    float rs = red_s[0];
    const f32x4* cx = (const f32x4*)&h_s[fp * 32];
    f32x4 pv = {0.f, 0.f, 0.f, 0.f};
#pragma unroll
    for (int d = 0; d < 8; ++d) pv = __builtin_elementwise_fma(cx[d], wf4[d], pv);
    float p = (pv.x + pv.z) + (pv.y + pv.w);
    p += __shfl_xor(p, 1);
    p += __shfl_xor(p, 2);
    if (fp == 0) outg[((size_t)b * 63 + 62) * 32 + fv] = fmaf(p, rs, fcbv);
  }
}

extern "C" void kernel_launch(void* const* d_in, const int* in_sizes, int n_in,
                              void* d_out, int out_size, void* d_ws, size_t ws_size,
                              hipStream_t stream) {
  const float* x = (const float*)d_in[0];
  const int* y = (const int*)d_in[1];
  const float* mean = (const float*)d_in[2];
  const float* stdv = (const float*)d_in[3];
  const float* w1 = (const float*)d_in[4];
  const float* b1 = (const float*)d_in[5];
  const float* w2 = (const float*)d_in[6];
  const float* b2 = (const float*)d_in[7];
  const float* wih = (const float*)d_in[8];
  const float* whh = (const float*)d_in[9];
  const float* bih = (const float*)d_in[10];
  const float* bhh = (const float*)d_in[11];
  const float* emb = (const float*)d_in[12];
  const float* dwih = (const float*)d_in[13];
  const float* dwhh = (const float*)d_in[14];
  const float* dbih = (const float*)d_in[15];
  const float* dbhh = (const float*)d_in[16];
  const float* fcw = (const float*)d_in[17];
  const float* fcb = (const float*)d_in[18];
  float* out = (float*)d_out;
  char* ws = (char*)d_ws;

  // ws layout (bytes); xp/ip overlap dead c1out region (both written after conv2).
  unsigned short* c1out = (unsigned short*)(ws + 0);              // 78,970,880 B
  float* xp = (float*)(ws + 0);                                   // 10,321,920 B (after conv2)
  float* ipg = (float*)(ws + 13762560);                           //  6,193,152 B
  unsigned short* wt2 = (unsigned short*)(ws + 78970880);         //    589,824 B
  unsigned short* wihB = (unsigned short*)(ws + 79560704);        //    884,736 B
  unsigned int* wpe = (unsigned int*)(ws + 80445440);             //     98,304 B
  unsigned int* wpd = (unsigned int*)(ws + 80543744);             //     98,304 B
  float* wdT = (float*)(ws + 80642048);                           //     49,152 B
  unsigned short* X2 = (unsigned short*)(ws + 80691200);          // 15,482,880 B

  prep_kernel<<<3120, 256, 0, stream>>>(w2, wih, whh, dwhh, dwih, wt2, wihB, wpe, wpd, wdT);
  conv1_kernel<<<dim3(31, 64), 256, 0, stream>>>(x, mean, stdv, w1, b1, c1out);
  conv2_kernel<<<dim3(15, 64), 256, 0, stream>>>(c1out, wt2, b2, X2);
  xp_kernel<<<dim3(105, 3), 256, 0, stream>>>(X2, wihB, bih, xp);
  ip_kernel<<<64 * 63, 384, 0, stream>>>(y, emb, wdT, dbih, ipg);
  rnn_kernel<<<64, 384, 0, stream>>>(xp, wpe, bhh, ipg, wpd, dbhh, fcw, fcb, out);
}